// Round 5
// baseline (33.756 us; speedup 1.0000x reference)
//
#include <hip/hip_runtime.h>
#include <cmath>

#define WS 11

typedef __attribute__((ext_vector_type(8))) short short8;   // 8 bf16 (4 VGPRs)
typedef __attribute__((ext_vector_type(4))) float f32x4;
typedef __attribute__((ext_vector_type(4))) unsigned int u32x4;

struct GaussW { float g[WS]; };

__device__ __forceinline__ unsigned cvt_pk_bf16(float lo, float hi) {
    unsigned r;
    asm("v_cvt_pk_bf16_f32 %0, %1, %2" : "=v"(r) : "v"(lo), "v"(hi));
    return r;
}

// 24576 rows x 512 px. Wave = 16 rows x 128 px strip; lane: m=lane&15 (row),
// g4=lane>>4 (k-slice). Conv as MFMA: D[16x16] = A[16x32 window] * B[32x16
// Toeplitz(g)]. 4 convs (u, v, u^2, v^2) share B; SSIM epilogue per D element.
__global__ __launch_bounds__(256) void ssim_mfma_kernel(
    const float* __restrict__ pred, const float* __restrict__ targ,
    GaussW gw, float* __restrict__ partials)
{
    const int t = threadIdx.x;
    const int lane = t & 63;
    const int wave = t >> 6;
    const int W = blockIdx.x * 4 + wave;        // 0..6143
    const int strip = W & 3;                    // 128-px strip in row
    const int rowgrp = W >> 2;                  // 0..1535
    const int m = lane & 15;
    const int g4 = lane >> 4;

    const float C1 = 0.0001f, C2 = 0.0009f;

    // B fragment (Toeplitz of gaussian): B[k][n] = g[k-n-3] (0 outside band),
    // n = lane&15, k = 8*g4 + j. Built once; bf16 via cvt_pk.
    short8 bfrag;
    {
        u32x4 bu;
        #pragma unroll
        for (int jj = 0; jj < 4; ++jj) {
            const int k0 = 8 * g4 + 2 * jj;
            float b0 = 0.f, b1 = 0.f;
            #pragma unroll
            for (int x = 0; x < WS; ++x) {
                b0 = (k0 - m - 3 == x) ? gw.g[x] : b0;
                b1 = (k0 - m - 2 == x) ? gw.g[x] : b1;
            }
            bu[jj] = cvt_pk_bf16(b0, b1);
        }
        bfrag = __builtin_bit_cast(short8, bu);
    }

    const long long row = (long long)rowgrp * 16 + m;
    const float* prow = pred + row * 512;
    const float* qrow = targ + row * 512;

    const f32x4 zero4 = {0.f, 0.f, 0.f, 0.f};
    float acc = 0.f;

    #pragma unroll
    for (int tile = 0; tile < 8; ++tile) {
        const int pix0 = strip * 128 + tile * 16;
        const int s = pix0 - 8 + 8 * g4;        // chunk start, multiple of 8
        const int sc = (s < 0) ? 0 : (s > 504 ? 504 : s);
        f32x4 p0 = *(const f32x4*)(prow + sc);
        f32x4 p1 = *(const f32x4*)(prow + sc + 4);
        f32x4 q0 = *(const f32x4*)(qrow + sc);
        f32x4 q1 = *(const f32x4*)(qrow + sc + 4);

        f32x4 u0 = p0 + q0, u1 = p1 + q1;
        f32x4 v0 = p0 - q0, v1 = p1 - q1;
        // fully-OOB chunks (s=-8 or s=512) only at the two row-edge tiles;
        // zero them (the reference's W zero-padding; B's zero band handles
        // taps beyond pad range).
        if ((strip == 0 && tile == 0) || (strip == 3 && tile == 7)) {
            const float msk = (s < 0 || s >= 512) ? 0.f : 1.f;
            u0 *= msk; u1 *= msk; v0 *= msk; v1 *= msk;
        }
        f32x4 su0 = u0 * u0, su1 = u1 * u1;
        f32x4 sv0 = v0 * v0, sv1 = v1 * v1;

        u32x4 au, av, asu, asv;
        #pragma unroll
        for (int jj = 0; jj < 2; ++jj) {
            au[jj]    = cvt_pk_bf16(u0[2 * jj], u0[2 * jj + 1]);
            au[2+jj]  = cvt_pk_bf16(u1[2 * jj], u1[2 * jj + 1]);
            av[jj]    = cvt_pk_bf16(v0[2 * jj], v0[2 * jj + 1]);
            av[2+jj]  = cvt_pk_bf16(v1[2 * jj], v1[2 * jj + 1]);
            asu[jj]   = cvt_pk_bf16(su0[2 * jj], su0[2 * jj + 1]);
            asu[2+jj] = cvt_pk_bf16(su1[2 * jj], su1[2 * jj + 1]);
            asv[jj]   = cvt_pk_bf16(sv0[2 * jj], sv0[2 * jj + 1]);
            asv[2+jj] = cvt_pk_bf16(sv1[2 * jj], sv1[2 * jj + 1]);
        }

        const f32x4 DA = __builtin_amdgcn_mfma_f32_16x16x32_bf16(
            __builtin_bit_cast(short8, au), bfrag, zero4, 0, 0, 0);
        const f32x4 DB = __builtin_amdgcn_mfma_f32_16x16x32_bf16(
            __builtin_bit_cast(short8, av), bfrag, zero4, 0, 0, 0);
        const f32x4 DSU = __builtin_amdgcn_mfma_f32_16x16x32_bf16(
            __builtin_bit_cast(short8, asu), bfrag, zero4, 0, 0, 0);
        const f32x4 DSV = __builtin_amdgcn_mfma_f32_16x16x32_bf16(
            __builtin_bit_cast(short8, asv), bfrag, zero4, 0, 0, 0);

        // A=mu1+mu2, B=mu1-mu2, SU=m11+2m12+m22, SV=m11-2m12+m22
        #pragma unroll
        for (int j = 0; j < 4; ++j) {
            const float A = DA[j], B = DB[j], SU = DSU[j], SV = DSV[j];
            const float a2 = A * A, b2 = B * B;
            const float d2 = a2 - b2, t2 = a2 + b2;       // 4mu12, 2(mu1²+mu2²)
            const float ds = SU - SV, ts = SU + SV;       // 4m12,  2(m11+m22)
            const float num1 = fmaf(0.5f, d2, C1);
            const float den1 = fmaf(0.5f, t2, C1);
            const float num2 = fmaf(0.5f, ds - d2, C2);
            const float den2 = fmaf(0.5f, ts - t2, C2);
            acc = fmaf(num1 * num2, __builtin_amdgcn_rcpf(den1 * den2), acc);
        }
    }

    #pragma unroll
    for (int off = 32; off > 0; off >>= 1)
        acc += __shfl_down(acc, off);
    __shared__ float wsum[4];
    if (lane == 0) wsum[wave] = acc;
    __syncthreads();
    if (t == 0)
        partials[blockIdx.x] = wsum[0] + wsum[1] + wsum[2] + wsum[3];
}

// Sum 1536 block partials in double; the 10 zero-pad rows per (b,c)
// contribute ssim == 1 exactly: 16*3*10*512 = 245760 elements.
// Total elements: 16*3*522*512 = 12828672.
__global__ __launch_bounds__(256) void ssim_final_kernel(
    const float* __restrict__ partials, float* __restrict__ out)
{
    const int t = threadIdx.x;
    double d = 0.0;
    #pragma unroll
    for (int i = 0; i < 6; ++i)
        d += (double)partials[t + 256 * i];
    #pragma unroll
    for (int off = 32; off > 0; off >>= 1)
        d += __shfl_down(d, off);
    __shared__ double wsumd[4];
    const int lane = t & 63, wave = t >> 6;
    if (lane == 0) wsumd[wave] = d;
    __syncthreads();
    if (t == 0) {
        const double s = wsumd[0] + wsumd[1] + wsumd[2] + wsumd[3] + 245760.0;
        out[0] = (float)(1.0 - s / 12828672.0);
    }
}

extern "C" void kernel_launch(void* const* d_in, const int* in_sizes, int n_in,
                              void* d_out, int out_size, void* d_ws, size_t ws_size,
                              hipStream_t stream) {
    const float* pred = (const float*)d_in[0];
    const float* targ = (const float*)d_in[1];
    float* out = (float*)d_out;
    float* partials = (float*)d_ws;   // 1536 floats

    // Gaussian window, exactly as the reference (sigma=1.5, ws=11).
    GaussW gw;
    double graw[WS], s = 0.0;
    for (int i = 0; i < WS; ++i) {
        const double c = (double)(i - WS / 2);
        graw[i] = exp(-c * c / (2.0 * 1.5 * 1.5));
        s += graw[i];
    }
    for (int i = 0; i < WS; ++i) gw.g[i] = (float)(graw[i] / s);

    ssim_mfma_kernel<<<1536, 256, 0, stream>>>(pred, targ, gw, partials);
    ssim_final_kernel<<<1, 256, 0, stream>>>(partials, out);
}

// Round 6
// 27.856 us; speedup vs baseline: 1.2118x; 1.2118x over previous
//
#include <hip/hip_runtime.h>
#include <cmath>

#define WS 11

typedef float v2f __attribute__((ext_vector_type(2)));

struct GaussPairs { unsigned long long gg[WS]; };  // (g,g) duplicated per tap

// Forced packed dual-f32 ops (gfx90a+/gfx950 VOP3P). Accumulator chain kept
// in VGPR pairs; the (g,g) multiplier comes from an SGPR pair (1 SGPR
// operand per VALU instruction is legal).
__device__ __forceinline__ v2f pk_fma_sg(unsigned long long g, v2f b, v2f c) {
    v2f d;
    asm("v_pk_fma_f32 %0, %1, %2, %3" : "=v"(d) : "s"(g), "v"(b), "v"(c));
    return d;
}
__device__ __forceinline__ v2f pk_mul(v2f a, v2f b) {
    v2f d;
    asm("v_pk_mul_f32 %0, %1, %2" : "=v"(d) : "v"(a), "v"(b));
    return d;
}

// 16*3*512 = 24576 rows of 512 floats. One wave (64 lanes) per row,
// 8 pixels per lane, 3 rows per wave, prefetch next row during compute.
// 4-conv identity: u=p+q, v=p-q; conv(u),conv(v),conv(u^2),conv(v^2)
// recover all five SSIM moments. (u,v) and (u^2,v^2) packed per pixel so
// each conv tap is exactly one v_pk_fma_f32.
__global__ __launch_bounds__(256) void ssim_row_kernel(
    const float* __restrict__ pred, const float* __restrict__ targ,
    GaussPairs gp, float* __restrict__ partials)
{
    const int t = threadIdx.x;
    const int lane = t & 63;
    const int wave = t >> 6;
    const int wave_id = blockIdx.x * 4 + wave;   // 0..8191
    const float C1 = 0.0001f, C2 = 0.0009f;

    const long long off = (long long)wave_id * 512 + 8 * lane;
    const float* prow = pred + off;
    const float* trow = targ + off;

    float4 P0 = *reinterpret_cast<const float4*>(prow);
    float4 P1 = *reinterpret_cast<const float4*>(prow + 4);
    float4 Q0 = *reinterpret_cast<const float4*>(trow);
    float4 Q1 = *reinterpret_cast<const float4*>(trow + 4);

    float acc = 0.f;
    #pragma unroll
    for (int r = 0; r < 3; ++r) {
        // prefetch next row (8192 rows apart) before computing this one
        float4 nP0, nP1, nQ0, nQ1;
        if (r < 2) {
            const float* pn = prow + (long long)(r + 1) * 8192 * 512;
            const float* tn = trow + (long long)(r + 1) * 8192 * 512;
            nP0 = *reinterpret_cast<const float4*>(pn);
            nP1 = *reinterpret_cast<const float4*>(pn + 4);
            nQ0 = *reinterpret_cast<const float4*>(tn);
            nQ1 = *reinterpret_cast<const float4*>(tn + 4);
        }

        // w[i] = (u,v), s[i] = (u^2,v^2); taps 0..17 cover pixels
        // [8*lane-5, 8*lane+12] of the row.
        v2f w[18], s[18];
        {
            const float pv[8] = {P0.x, P0.y, P0.z, P0.w, P1.x, P1.y, P1.z, P1.w};
            const float qv[8] = {Q0.x, Q0.y, Q0.z, Q0.w, Q1.x, Q1.y, Q1.z, Q1.w};
            #pragma unroll
            for (int i = 0; i < 8; ++i) {
                w[5 + i].x = pv[i] + qv[i];
                w[5 + i].y = pv[i] - qv[i];
            }
        }
        // halos from neighbor lanes; zero at row edges (the W zero-padding)
        #pragma unroll
        for (int i = 0; i < 5; ++i) {
            float lu = __shfl_up(w[8 + i].x, 1);    // lane-1 pixels 3..7
            float lv = __shfl_up(w[8 + i].y, 1);
            float ru = __shfl_down(w[5 + i].x, 1);  // lane+1 pixels 0..4
            float rv = __shfl_down(w[5 + i].y, 1);
            w[i].x      = (lane == 0)  ? 0.f : lu;
            w[i].y      = (lane == 0)  ? 0.f : lv;
            w[13 + i].x = (lane == 63) ? 0.f : ru;
            w[13 + i].y = (lane == 63) ? 0.f : rv;
        }
        #pragma unroll
        for (int i = 0; i < 18; ++i) s[i] = pk_mul(w[i], w[i]);

        #pragma unroll
        for (int px = 0; px < 8; ++px) {
            v2f AB  = {0.f, 0.f};   // (Σg·u, Σg·v)   = (mu1+mu2, mu1-mu2)
            v2f SUV = {0.f, 0.f};   // (Σg·u², Σg·v²)
            #pragma unroll
            for (int k = 0; k < WS; ++k) {
                AB  = pk_fma_sg(gp.gg[k], w[px + k], AB);
                SUV = pk_fma_sg(gp.gg[k], s[px + k], SUV);
            }
            const v2f ab2 = pk_mul(AB, AB);      // (A^2, B^2)
            const float d2 = ab2.x - ab2.y;      // 4*mu1*mu2
            const float t2 = ab2.x + ab2.y;      // 2*(mu1^2+mu2^2)
            const float ds = SUV.x - SUV.y;      // 4*m12
            const float ts = SUV.x + SUV.y;      // 2*(m11+m22)
            const float num1 = fmaf(0.5f, d2, C1);        // 2*mu12+C1
            const float den1 = fmaf(0.5f, t2, C1);        // mu1^2+mu2^2+C1
            const float num2 = fmaf(0.5f, ds - d2, C2);   // 2*s12+C2
            const float den2 = fmaf(0.5f, ts - t2, C2);   // s1+s2+C2
            acc = fmaf(num1 * num2, __builtin_amdgcn_rcpf(den1 * den2), acc);
        }

        if (r < 2) { P0 = nP0; P1 = nP1; Q0 = nQ0; Q1 = nQ1; }
    }

    // wave reduction, then block combine, partials (no atomics)
    #pragma unroll
    for (int offr = 32; offr > 0; offr >>= 1)
        acc += __shfl_down(acc, offr);
    __shared__ float wsum[4];
    if (lane == 0) wsum[wave] = acc;
    __syncthreads();
    if (t == 0)
        partials[blockIdx.x] = wsum[0] + wsum[1] + wsum[2] + wsum[3];
}

// Sum 2048 block partials in double; the 10 zero-pad rows per (b,c)
// contribute ssim == 1 exactly: 16*3*10*512 = 245760 elements.
// Total elements: 16*3*522*512 = 12828672.
__global__ __launch_bounds__(256) void ssim_final_kernel(
    const float* __restrict__ partials, float* __restrict__ out)
{
    const int t = threadIdx.x;
    double d = 0.0;
    #pragma unroll
    for (int i = 0; i < 8; ++i)
        d += (double)partials[t + 256 * i];
    #pragma unroll
    for (int offr = 32; offr > 0; offr >>= 1)
        d += __shfl_down(d, offr);
    __shared__ double wsumd[4];
    const int lane = t & 63, wave = t >> 6;
    if (lane == 0) wsumd[wave] = d;
    __syncthreads();
    if (t == 0) {
        const double s = wsumd[0] + wsumd[1] + wsumd[2] + wsumd[3] + 245760.0;
        out[0] = (float)(1.0 - s / 12828672.0);
    }
}

extern "C" void kernel_launch(void* const* d_in, const int* in_sizes, int n_in,
                              void* d_out, int out_size, void* d_ws, size_t ws_size,
                              hipStream_t stream) {
    const float* pred = (const float*)d_in[0];
    const float* targ = (const float*)d_in[1];
    float* out = (float*)d_out;
    float* partials = (float*)d_ws;   // 2048 floats

    // Gaussian window, exactly as the reference (sigma=1.5, ws=11),
    // duplicated into (g,g) 64-bit pairs for packed-f32 SGPR operands.
    GaussPairs gp;
    double graw[WS], s = 0.0;
    for (int i = 0; i < WS; ++i) {
        const double c = (double)(i - WS / 2);
        graw[i] = exp(-c * c / (2.0 * 1.5 * 1.5));
        s += graw[i];
    }
    for (int i = 0; i < WS; ++i) {
        const float g = (float)(graw[i] / s);
        unsigned int gb;
        __builtin_memcpy(&gb, &g, 4);
        gp.gg[i] = ((unsigned long long)gb << 32) | gb;
    }

    ssim_row_kernel<<<2048, 256, 0, stream>>>(pred, targ, gp, partials);
    ssim_final_kernel<<<1, 256, 0, stream>>>(partials, out);
}